// Round 2
// baseline (2541.009 us; speedup 1.0000x reference)
//
#include <hip/hip_runtime.h>
#include <hip/hip_bf16.h>

#define N_TOK 16384
#define H_DIM 768
#define I_DIM 3072
#define NEXP 8

typedef short bf16x8 __attribute__((ext_vector_type(8)));
typedef float f32x4 __attribute__((ext_vector_type(4)));

__device__ __forceinline__ unsigned short f2bf(float f) {
    unsigned int u = __float_as_uint(f);
    u += 0x7fffu + ((u >> 16) & 1u);
    return (unsigned short)(u >> 16);
}

__device__ __forceinline__ float gelu_tanh(float v) {
    float u = 0.7978845608028654f * (v + 0.044715f * v * v * v);
    float t = __expf(2.0f * fminf(u, 15.0f));
    return 0.5f * v * (1.0f + (t - 1.0f) / (t + 1.0f));
}

__device__ __forceinline__ void gll16(const void* g, void* l) {
    __builtin_amdgcn_global_load_lds(
        (const __attribute__((address_space(1))) unsigned int*)g,
        (__attribute__((address_space(3))) unsigned int*)l, 16, 0, 0);
}

// ---------------- Router: logits -> softmax -> top2 -> weights (+ fused x->bf16) ----
__global__ __launch_bounds__(256) void moe_router(
    const float* __restrict__ x, const float* __restrict__ gw,
    unsigned short* __restrict__ xbf,
    int* __restrict__ topidx, float* __restrict__ topw,
    float* __restrict__ cnt_psum /* [16] zeroed: counts 0..7, psum 8..15 */)
{
    const int lane = threadIdx.x & 63;
    const int wid = threadIdx.x >> 6;
    const int wglobal = blockIdx.x * 4 + wid;
    const int NWAVES = gridDim.x * 4;

    float gwl[8][12];
#pragma unroll
    for (int e = 0; e < 8; ++e)
#pragma unroll
        for (int j = 0; j < 12; ++j)
            gwl[e][j] = gw[e * H_DIM + j * 64 + lane];

    float lcnt[8], lps[8];
#pragma unroll
    for (int e = 0; e < 8; ++e) { lcnt[e] = 0.f; lps[e] = 0.f; }

    for (int t = wglobal; t < N_TOK; t += NWAVES) {
        float acc[8] = {0.f, 0.f, 0.f, 0.f, 0.f, 0.f, 0.f, 0.f};
#pragma unroll
        for (int j = 0; j < 12; ++j) {
            float xv = x[(size_t)t * H_DIM + j * 64 + lane];
            xbf[(size_t)t * H_DIM + j * 64 + lane] = f2bf(xv);
#pragma unroll
            for (int e = 0; e < 8; ++e) acc[e] += xv * gwl[e][j];
        }
#pragma unroll
        for (int off = 32; off >= 1; off >>= 1)
#pragma unroll
            for (int e = 0; e < 8; ++e) acc[e] += __shfl_xor(acc[e], off, 64);

        // top-2 on logits (same order as probs; strict > keeps lowest index on ties)
        int e0 = 0;
#pragma unroll
        for (int e = 1; e < 8; ++e) if (acc[e] > acc[e0]) e0 = e;
        int e1 = (e0 == 0) ? 1 : 0;
#pragma unroll
        for (int e = 0; e < 8; ++e) if (e != e0 && acc[e] > acc[e1]) e1 = e;

        float mx = acc[0];
#pragma unroll
        for (int e = 1; e < 8; ++e) mx = fmaxf(mx, acc[e]);
        float p[8]; float s = 0.f;
#pragma unroll
        for (int e = 0; e < 8; ++e) { p[e] = expf(acc[e] - mx); s += p[e]; }
        float inv = 1.0f / s;
#pragma unroll
        for (int e = 0; e < 8; ++e) p[e] *= inv;

        float wsum = p[e0] + p[e1];
        if (lane == 0) {
            topidx[2 * t] = e0; topidx[2 * t + 1] = e1;
            topw[2 * t] = p[e0] / wsum; topw[2 * t + 1] = p[e1] / wsum;
            lcnt[e0] += 1.f; lcnt[e1] += 1.f;
#pragma unroll
            for (int e = 0; e < 8; ++e) lps[e] += p[e];
        }
    }
    if (lane == 0) {
#pragma unroll
        for (int e = 0; e < 8; ++e) {
            atomicAdd(&cnt_psum[e], lcnt[e]);
            atomicAdd(&cnt_psum[8 + e], lps[e]);
        }
    }
}

// ---------------- offsets + aux loss ----------------
__global__ void moe_finalize(const float* __restrict__ cnt_psum,
                             int* __restrict__ offs, float* __restrict__ aux_out)
{
    float aux = 0.f; int run = 0;
    for (int e = 0; e < 8; ++e) {
        float c = cnt_psum[e];
        aux += (c / (float)(N_TOK * 2)) * (cnt_psum[8 + e] / (float)N_TOK);
        offs[e] = run;
        run += (int)(c + 0.5f);
    }
    offs[8] = run;
    *aux_out = 0.01f * 8.0f * aux;
}

// ---------------- deterministic permutation (one block per expert) ----------------
__global__ __launch_bounds__(256) void moe_permute(
    const int* __restrict__ topidx, const float* __restrict__ topw,
    const int* __restrict__ offs, int* __restrict__ perm, float* __restrict__ pw)
{
    const int e = blockIdx.x;
    const int tid = threadIdx.x;
    const int lane = tid & 63, wid = tid >> 6;
    __shared__ int wsum[4];
    __shared__ int sbase;
    if (tid == 0) sbase = offs[e];
    __syncthreads();
    for (int t0 = 0; t0 < N_TOK; t0 += 256) {
        const int t = t0 + tid;
        int slot = -1;
        if (topidx[2 * t] == e) slot = 0;
        else if (topidx[2 * t + 1] == e) slot = 1;
        unsigned long long m = __ballot(slot >= 0);
        int before = __popcll(m & ((1ull << lane) - 1ull));
        if (lane == 0) wsum[wid] = __popcll(m);
        __syncthreads();
        int wprev = 0;
        for (int w = 0; w < wid; ++w) wprev += wsum[w];
        int total = wsum[0] + wsum[1] + wsum[2] + wsum[3];
        if (slot >= 0) {
            int r = sbase + wprev + before;
            perm[r] = t;
            pw[r] = topw[2 * t + slot];
        }
        __syncthreads();
        if (tid == 0) sbase += total;
        __syncthreads();
    }
}

// ---------------- fp32 -> bf16 convert ----------------
__global__ __launch_bounds__(256) void moe_cvt(const float* __restrict__ in,
                                               unsigned short* __restrict__ out, int n)
{
    int idx = (blockIdx.x * 256 + threadIdx.x) * 4;
    const int stride = gridDim.x * 1024;
    for (; idx < n; idx += stride) {
        float4 v = *(const float4*)(in + idx);
        ushort4 o;
        o.x = f2bf(v.x); o.y = f2bf(v.y); o.z = f2bf(v.z); o.w = f2bf(v.w);
        *(ushort4*)(out + idx) = o;
    }
}

// ---------------- GEMM1: h = gelu(gather(x) @ w1[e]^T) -> bf16 ----------------
__global__ __launch_bounds__(256) void moe_gemm1(
    const unsigned short* __restrict__ xbf,
    const unsigned short* __restrict__ w1bf,
    const int* __restrict__ perm, const int* __restrict__ offs,
    unsigned short* __restrict__ hbuf, int chunk_base, int ichunk)
{
    const int e = blockIdx.z;
    const int off = offs[e];
    const int n_e = offs[e + 1] - off;
    const int rt = blockIdx.y;
    if (rt * 128 >= n_e) return;
    const int ct = blockIdx.x;

    __shared__ __align__(16) unsigned short As[128 * 64];
    __shared__ __align__(16) unsigned short Bs[128 * 64];

    const int tid = threadIdx.x;
    const int lane = tid & 63;
    const int wid = tid >> 6;
    const int wr = wid >> 1, wc = wid & 1;
    const int trow = tid >> 3;        // 0..31
    const int tcol = (tid & 7) * 8;   // 0..56

    const unsigned short* aptr[4];
    const unsigned short* bptr[4];
#pragma unroll
    for (int i = 0; i < 4; ++i) {
        int lr = rt * 128 + i * 32 + trow;
        if (lr >= n_e) lr = n_e - 1;
        const int token = perm[off + lr];
        aptr[i] = xbf + (size_t)token * H_DIM + tcol;
        const int n = chunk_base + ct * 128 + i * 32 + trow;
        bptr[i] = w1bf + ((size_t)e * I_DIM + n) * H_DIM + tcol;
    }
    unsigned short* As_dst = As + tid * 8;
    unsigned short* Bs_dst = Bs + tid * 8;

    f32x4 acc[4][4] = {};

    for (int kk = 0; kk < H_DIM; kk += 64) {
#pragma unroll
        for (int i = 0; i < 4; ++i) gll16(aptr[i] + kk, As_dst + i * 2048);
#pragma unroll
        for (int i = 0; i < 4; ++i) gll16(bptr[i] + kk, Bs_dst + i * 2048);
        __syncthreads();
        const unsigned short* Ab = As + (wr * 64 + (lane & 15)) * 64 + (lane >> 4) * 8;
        const unsigned short* Bb = Bs + (wc * 64 + (lane & 15)) * 64 + (lane >> 4) * 8;
#pragma unroll
        for (int ksub = 0; ksub < 2; ++ksub) {
            bf16x8 a[4], b[4];
#pragma unroll
            for (int i = 0; i < 4; ++i) a[i] = *(const bf16x8*)(Ab + i * 16 * 64 + ksub * 32);
#pragma unroll
            for (int j = 0; j < 4; ++j) b[j] = *(const bf16x8*)(Bb + j * 16 * 64 + ksub * 32);
#pragma unroll
            for (int i = 0; i < 4; ++i)
#pragma unroll
                for (int j = 0; j < 4; ++j)
                    acc[i][j] = __builtin_amdgcn_mfma_f32_16x16x32_bf16(a[i], b[j], acc[i][j], 0, 0, 0);
        }
        __syncthreads();
    }

    const int rbase = rt * 128 + wr * 64 + (lane >> 4) * 4;
    const int cbase = ct * 128 + wc * 64 + (lane & 15);
#pragma unroll
    for (int i = 0; i < 4; ++i) {
#pragma unroll
        for (int r = 0; r < 4; ++r) {
            const int lr = rbase + i * 16 + r;
            if (lr < n_e) {
                unsigned short* dst = hbuf + (size_t)(off + lr) * ichunk + cbase;
#pragma unroll
                for (int j = 0; j < 4; ++j)
                    dst[j * 16] = f2bf(gelu_tanh(acc[i][j][r]));
            }
        }
    }
}

// ---------------- GEMM2: y += w * (h @ w2[e]^T) (weighted scatter-add) ----------------
__global__ __launch_bounds__(256) void moe_gemm2(
    const unsigned short* __restrict__ hbuf,
    const unsigned short* __restrict__ w2bf,
    const int* __restrict__ perm, const float* __restrict__ pw,
    const int* __restrict__ offs, float* __restrict__ y,
    int chunk_base, int ichunk)
{
    const int e = blockIdx.z;
    const int off = offs[e];
    const int n_e = offs[e + 1] - off;
    const int rt = blockIdx.y;
    if (rt * 128 >= n_e) return;
    const int ct = blockIdx.x;  // 0..5

    __shared__ __align__(16) unsigned short As[128 * 64];
    __shared__ __align__(16) unsigned short Bs[128 * 64];

    const int tid = threadIdx.x;
    const int lane = tid & 63;
    const int wid = tid >> 6;
    const int wr = wid >> 1, wc = wid & 1;
    const int trow = tid >> 3, tcol = (tid & 7) * 8;

    const unsigned short* aptr[4];
    const unsigned short* bptr[4];
#pragma unroll
    for (int i = 0; i < 4; ++i) {
        int lr = rt * 128 + i * 32 + trow;
        if (lr >= n_e) lr = n_e - 1;
        aptr[i] = hbuf + (size_t)(off + lr) * ichunk + tcol;
        const int n = ct * 128 + i * 32 + trow;
        bptr[i] = w2bf + ((size_t)e * H_DIM + n) * I_DIM + chunk_base + tcol;
    }
    unsigned short* As_dst = As + tid * 8;
    unsigned short* Bs_dst = Bs + tid * 8;

    f32x4 acc[4][4] = {};

    for (int kk = 0; kk < ichunk; kk += 64) {
#pragma unroll
        for (int i = 0; i < 4; ++i) gll16(aptr[i] + kk, As_dst + i * 2048);
#pragma unroll
        for (int i = 0; i < 4; ++i) gll16(bptr[i] + kk, Bs_dst + i * 2048);
        __syncthreads();
        const unsigned short* Ab = As + (wr * 64 + (lane & 15)) * 64 + (lane >> 4) * 8;
        const unsigned short* Bb = Bs + (wc * 64 + (lane & 15)) * 64 + (lane >> 4) * 8;
#pragma unroll
        for (int ksub = 0; ksub < 2; ++ksub) {
            bf16x8 a[4], b[4];
#pragma unroll
            for (int i = 0; i < 4; ++i) a[i] = *(const bf16x8*)(Ab + i * 16 * 64 + ksub * 32);
#pragma unroll
            for (int j = 0; j < 4; ++j) b[j] = *(const bf16x8*)(Bb + j * 16 * 64 + ksub * 32);
#pragma unroll
            for (int i = 0; i < 4; ++i)
#pragma unroll
                for (int j = 0; j < 4; ++j)
                    acc[i][j] = __builtin_amdgcn_mfma_f32_16x16x32_bf16(a[i], b[j], acc[i][j], 0, 0, 0);
        }
        __syncthreads();
    }

    const int rbase = rt * 128 + wr * 64 + (lane >> 4) * 4;
    const int cbase = ct * 128 + wc * 64 + (lane & 15);
#pragma unroll
    for (int i = 0; i < 4; ++i) {
#pragma unroll
        for (int r = 0; r < 4; ++r) {
            const int lr = rbase + i * 16 + r;
            if (lr < n_e) {
                const int token = perm[off + lr];
                const float w = pw[off + lr];
                float* dst = y + (size_t)token * H_DIM + cbase;
#pragma unroll
                for (int j = 0; j < 4; ++j)
                    atomicAdd(dst + j * 16, w * acc[i][j][r]);
            }
        }
    }
}

extern "C" void kernel_launch(void* const* d_in, const int* in_sizes, int n_in,
                              void* d_out, int out_size, void* d_ws, size_t ws_size,
                              hipStream_t stream) {
    const float* x  = (const float*)d_in[0];
    const float* gw = (const float*)d_in[1];
    const float* w1 = (const float*)d_in[2];
    const float* w2 = (const float*)d_in[3];
    float* y = (float*)d_out;  // [N_TOK*H_DIM] + aux at [N_TOK*H_DIM]

    // ---- workspace layout (all 16B-aligned sizes) ----
    char* base = (char*)d_ws;
    size_t o = 0;
    unsigned short* xbf  = (unsigned short*)(base + o); o += (size_t)N_TOK * H_DIM * 2;
    unsigned short* w1bf = (unsigned short*)(base + o); o += (size_t)NEXP * I_DIM * H_DIM * 2;
    unsigned short* w2bf = (unsigned short*)(base + o); o += (size_t)NEXP * H_DIM * I_DIM * 2;
    int*   topidx = (int*)(base + o);   o += (size_t)N_TOK * 2 * 4;
    float* topw   = (float*)(base + o); o += (size_t)N_TOK * 2 * 4;
    int*   perm   = (int*)(base + o);   o += (size_t)N_TOK * 2 * 4;
    float* pw     = (float*)(base + o); o += (size_t)N_TOK * 2 * 4;
    float* cnt_psum = (float*)(base + o); o += 64;
    int*   offs     = (int*)(base + o);   o += 64;
    unsigned short* hbuf = (unsigned short*)(base + o);
    size_t remain = (ws_size > o) ? (ws_size - o) : 0;

    // pick largest I-chunk that fits: h buffer = 2N * ichunk * 2 bytes
    const int opts[5] = {3072, 1536, 768, 384, 128};
    int ichunk = 128;
    for (int c = 0; c < 5; ++c) {
        if ((size_t)2 * N_TOK * opts[c] * 2 <= remain) { ichunk = opts[c]; break; }
    }

    hipMemsetAsync(d_out, 0, (size_t)out_size * 4, stream);
    hipMemsetAsync(cnt_psum, 0, 64, stream);

    // router fuses the x fp32->bf16 convert
    moe_router<<<2048, 256, 0, stream>>>(x, gw, xbf, topidx, topw, cnt_psum);

    moe_cvt<<<2048, 256, 0, stream>>>(w1, w1bf, NEXP * I_DIM * H_DIM);
    moe_cvt<<<2048, 256, 0, stream>>>(w2, w2bf, NEXP * H_DIM * I_DIM);

    moe_finalize<<<1, 1, 0, stream>>>(cnt_psum, offs, y + (size_t)N_TOK * H_DIM);
    moe_permute<<<8, 256, 0, stream>>>(topidx, topw, offs, perm, pw);

    for (int cb = 0; cb < I_DIM; cb += ichunk) {
        moe_gemm1<<<dim3(ichunk / 128, 128, NEXP), 256, 0, stream>>>(
            xbf, w1bf, perm, offs, hbuf, cb, ichunk);
        moe_gemm2<<<dim3(H_DIM / 128, 128, NEXP), 256, 0, stream>>>(
            hbuf, w2bf, perm, pw, offs, y, cb, ichunk);
    }
}

// Round 3
// 1670.655 us; speedup vs baseline: 1.5210x; 1.5210x over previous
//
#include <hip/hip_runtime.h>
#include <hip/hip_bf16.h>

#define N_TOK 16384
#define H_DIM 768
#define I_DIM 3072
#define NEXP 8

typedef short bf16x8 __attribute__((ext_vector_type(8)));
typedef float f32x4 __attribute__((ext_vector_type(4)));

__device__ __forceinline__ unsigned short f2bf(float f) {
    unsigned int u = __float_as_uint(f);
    u += 0x7fffu + ((u >> 16) & 1u);
    return (unsigned short)(u >> 16);
}

__device__ __forceinline__ float gelu_tanh(float v) {
    float u = 0.7978845608028654f * (v + 0.044715f * v * v * v);
    float t = __expf(2.0f * fminf(u, 15.0f));
    return 0.5f * v * (1.0f + (t - 1.0f) / (t + 1.0f));
}

__device__ __forceinline__ void gll16(const void* g, void* l) {
    __builtin_amdgcn_global_load_lds(
        (const __attribute__((address_space(1))) unsigned int*)g,
        (__attribute__((address_space(3))) unsigned int*)l, 16, 0, 0);
}

// ---------------- Router: logits -> softmax -> top2 -> weights (+ fused x->bf16) ----
// gw staged in LDS (24 KB); x read as float4, xbf written as ushort4. No spill.
__global__ __launch_bounds__(256) void moe_router(
    const float* __restrict__ x, const float* __restrict__ gw,
    unsigned short* __restrict__ xbf,
    int* __restrict__ topidx, float* __restrict__ topw,
    float* __restrict__ cnt_psum /* [16] zeroed: counts 0..7, psum 8..15 */)
{
    __shared__ float gws[NEXP * H_DIM];  // 24 KB
    const int tid = threadIdx.x;
    for (int i = tid * 4; i < NEXP * H_DIM; i += 1024)
        *(float4*)(gws + i) = *(const float4*)(gw + i);
    __syncthreads();

    const int lane = tid & 63;
    const int wid = tid >> 6;
    const int wglobal = blockIdx.x * 4 + wid;
    const int NWAVES = gridDim.x * 4;

    float lcnt[8], lps[8];
#pragma unroll
    for (int e = 0; e < 8; ++e) { lcnt[e] = 0.f; lps[e] = 0.f; }

    for (int t = wglobal; t < N_TOK; t += NWAVES) {
        float acc[8] = {0.f, 0.f, 0.f, 0.f, 0.f, 0.f, 0.f, 0.f};
#pragma unroll
        for (int j = 0; j < 3; ++j) {
            const int col = j * 256 + lane * 4;
            float4 xv = *(const float4*)(x + (size_t)t * H_DIM + col);
            ushort4 o;
            o.x = f2bf(xv.x); o.y = f2bf(xv.y); o.z = f2bf(xv.z); o.w = f2bf(xv.w);
            *(ushort4*)(xbf + (size_t)t * H_DIM + col) = o;
#pragma unroll
            for (int e = 0; e < 8; ++e) {
                float4 g = *(const float4*)(gws + e * H_DIM + col);
                acc[e] += xv.x * g.x + xv.y * g.y + xv.z * g.z + xv.w * g.w;
            }
        }
#pragma unroll
        for (int off = 32; off >= 1; off >>= 1)
#pragma unroll
            for (int e = 0; e < 8; ++e) acc[e] += __shfl_xor(acc[e], off, 64);

        // top-2 on logits (same order as probs; strict > keeps lowest index on ties)
        int e0 = 0;
#pragma unroll
        for (int e = 1; e < 8; ++e) if (acc[e] > acc[e0]) e0 = e;
        int e1 = (e0 == 0) ? 1 : 0;
#pragma unroll
        for (int e = 0; e < 8; ++e) if (e != e0 && acc[e] > acc[e1]) e1 = e;

        float mx = acc[0];
#pragma unroll
        for (int e = 1; e < 8; ++e) mx = fmaxf(mx, acc[e]);
        float p[8]; float s = 0.f;
#pragma unroll
        for (int e = 0; e < 8; ++e) { p[e] = expf(acc[e] - mx); s += p[e]; }
        float inv = 1.0f / s;
#pragma unroll
        for (int e = 0; e < 8; ++e) p[e] *= inv;

        float wsum = p[e0] + p[e1];
        if (lane == 0) {
            topidx[2 * t] = e0; topidx[2 * t + 1] = e1;
            topw[2 * t] = p[e0] / wsum; topw[2 * t + 1] = p[e1] / wsum;
            lcnt[e0] += 1.f; lcnt[e1] += 1.f;
#pragma unroll
            for (int e = 0; e < 8; ++e) lps[e] += p[e];
        }
    }
    if (lane == 0) {
#pragma unroll
        for (int e = 0; e < 8; ++e) {
            atomicAdd(&cnt_psum[e], lcnt[e]);
            atomicAdd(&cnt_psum[8 + e], lps[e]);
        }
    }
}

// ---------------- offsets + aux loss ----------------
__global__ void moe_finalize(const float* __restrict__ cnt_psum,
                             int* __restrict__ offs, float* __restrict__ aux_out)
{
    float aux = 0.f; int run = 0;
    for (int e = 0; e < 8; ++e) {
        float c = cnt_psum[e];
        aux += (c / (float)(N_TOK * 2)) * (cnt_psum[8 + e] / (float)N_TOK);
        offs[e] = run;
        run += (int)(c + 0.5f);
    }
    offs[8] = run;
    *aux_out = 0.01f * 8.0f * aux;
}

// ---------------- deterministic permutation (one block per expert) ----------------
__global__ __launch_bounds__(256) void moe_permute(
    const int* __restrict__ topidx, const float* __restrict__ topw,
    const int* __restrict__ offs, int* __restrict__ perm, float* __restrict__ pw)
{
    const int e = blockIdx.x;
    const int tid = threadIdx.x;
    const int lane = tid & 63, wid = tid >> 6;
    __shared__ int wsum[4];
    __shared__ int sbase;
    if (tid == 0) sbase = offs[e];
    __syncthreads();
    for (int t0 = 0; t0 < N_TOK; t0 += 256) {
        const int t = t0 + tid;
        int slot = -1;
        if (topidx[2 * t] == e) slot = 0;
        else if (topidx[2 * t + 1] == e) slot = 1;
        unsigned long long m = __ballot(slot >= 0);
        int before = __popcll(m & ((1ull << lane) - 1ull));
        if (lane == 0) wsum[wid] = __popcll(m);
        __syncthreads();
        int wprev = 0;
        for (int w = 0; w < wid; ++w) wprev += wsum[w];
        int total = wsum[0] + wsum[1] + wsum[2] + wsum[3];
        if (slot >= 0) {
            int r = sbase + wprev + before;
            perm[r] = t;
            pw[r] = topw[2 * t + slot];
        }
        __syncthreads();
        if (tid == 0) sbase += total;
        __syncthreads();
    }
}

// ---------------- fp32 -> bf16 convert ----------------
__global__ __launch_bounds__(256) void moe_cvt(const float* __restrict__ in,
                                               unsigned short* __restrict__ out, int n)
{
    int idx = (blockIdx.x * 256 + threadIdx.x) * 4;
    const int stride = gridDim.x * 1024;
    for (; idx < n; idx += stride) {
        float4 v = *(const float4*)(in + idx);
        ushort4 o;
        o.x = f2bf(v.x); o.y = f2bf(v.y); o.z = f2bf(v.z); o.w = f2bf(v.w);
        *(ushort4*)(out + idx) = o;
    }
}

// ---------------- GEMM1: h = gelu(gather(x) @ w1[e]^T) -> bf16 ----------------
__global__ __launch_bounds__(256) void moe_gemm1(
    const unsigned short* __restrict__ xbf,
    const unsigned short* __restrict__ w1bf,
    const int* __restrict__ perm, const int* __restrict__ offs,
    unsigned short* __restrict__ hbuf, int chunk_base, int ichunk)
{
    const int e = blockIdx.z;
    const int off = offs[e];
    const int n_e = offs[e + 1] - off;
    const int rt = blockIdx.y;
    if (rt * 128 >= n_e) return;
    const int ct = blockIdx.x;

    __shared__ __align__(16) unsigned short As[128 * 64];
    __shared__ __align__(16) unsigned short Bs[128 * 64];

    const int tid = threadIdx.x;
    const int lane = tid & 63;
    const int wid = tid >> 6;
    const int wr = wid >> 1, wc = wid & 1;
    const int trow = tid >> 3;        // 0..31
    const int tcol = (tid & 7) * 8;   // 0..56

    const unsigned short* aptr[4];
    const unsigned short* bptr[4];
#pragma unroll
    for (int i = 0; i < 4; ++i) {
        int lr = rt * 128 + i * 32 + trow;
        if (lr >= n_e) lr = n_e - 1;
        const int token = perm[off + lr];
        aptr[i] = xbf + (size_t)token * H_DIM + tcol;
        const int n = chunk_base + ct * 128 + i * 32 + trow;
        bptr[i] = w1bf + ((size_t)e * I_DIM + n) * H_DIM + tcol;
    }
    unsigned short* As_dst = As + tid * 8;
    unsigned short* Bs_dst = Bs + tid * 8;

    f32x4 acc[4][4] = {};

    for (int kk = 0; kk < H_DIM; kk += 64) {
#pragma unroll
        for (int i = 0; i < 4; ++i) gll16(aptr[i] + kk, As_dst + i * 2048);
#pragma unroll
        for (int i = 0; i < 4; ++i) gll16(bptr[i] + kk, Bs_dst + i * 2048);
        __syncthreads();
        const unsigned short* Ab = As + (wr * 64 + (lane & 15)) * 64 + (lane >> 4) * 8;
        const unsigned short* Bb = Bs + (wc * 64 + (lane & 15)) * 64 + (lane >> 4) * 8;
#pragma unroll
        for (int ksub = 0; ksub < 2; ++ksub) {
            bf16x8 a[4], b[4];
#pragma unroll
            for (int i = 0; i < 4; ++i) a[i] = *(const bf16x8*)(Ab + i * 16 * 64 + ksub * 32);
#pragma unroll
            for (int j = 0; j < 4; ++j) b[j] = *(const bf16x8*)(Bb + j * 16 * 64 + ksub * 32);
#pragma unroll
            for (int i = 0; i < 4; ++i)
#pragma unroll
                for (int j = 0; j < 4; ++j)
                    acc[i][j] = __builtin_amdgcn_mfma_f32_16x16x32_bf16(a[i], b[j], acc[i][j], 0, 0, 0);
        }
        __syncthreads();
    }

    const int rbase = rt * 128 + wr * 64 + (lane >> 4) * 4;
    const int cbase = ct * 128 + wc * 64 + (lane & 15);
#pragma unroll
    for (int i = 0; i < 4; ++i) {
#pragma unroll
        for (int r = 0; r < 4; ++r) {
            const int lr = rbase + i * 16 + r;
            if (lr < n_e) {
                unsigned short* dst = hbuf + (size_t)(off + lr) * ichunk + cbase;
#pragma unroll
                for (int j = 0; j < 4; ++j)
                    dst[j * 16] = f2bf(gelu_tanh(acc[i][j][r]));
            }
        }
    }
}

// ---------------- GEMM2: y += w * (h @ w2[e]^T) (weighted scatter-add) ----------------
__global__ __launch_bounds__(256) void moe_gemm2(
    const unsigned short* __restrict__ hbuf,
    const unsigned short* __restrict__ w2bf,
    const int* __restrict__ perm, const float* __restrict__ pw,
    const int* __restrict__ offs, float* __restrict__ y,
    int chunk_base, int ichunk)
{
    const int e = blockIdx.z;
    const int off = offs[e];
    const int n_e = offs[e + 1] - off;
    const int rt = blockIdx.y;
    if (rt * 128 >= n_e) return;
    const int ct = blockIdx.x;  // 0..5

    __shared__ __align__(16) unsigned short As[128 * 64];
    __shared__ __align__(16) unsigned short Bs[128 * 64];

    const int tid = threadIdx.x;
    const int lane = tid & 63;
    const int wid = tid >> 6;
    const int wr = wid >> 1, wc = wid & 1;
    const int trow = tid >> 3, tcol = (tid & 7) * 8;

    const unsigned short* aptr[4];
    const unsigned short* bptr[4];
#pragma unroll
    for (int i = 0; i < 4; ++i) {
        int lr = rt * 128 + i * 32 + trow;
        if (lr >= n_e) lr = n_e - 1;
        aptr[i] = hbuf + (size_t)(off + lr) * ichunk + tcol;
        const int n = ct * 128 + i * 32 + trow;
        bptr[i] = w2bf + ((size_t)e * H_DIM + n) * I_DIM + chunk_base + tcol;
    }
    unsigned short* As_dst = As + tid * 8;
    unsigned short* Bs_dst = Bs + tid * 8;

    f32x4 acc[4][4] = {};

    for (int kk = 0; kk < ichunk; kk += 64) {
#pragma unroll
        for (int i = 0; i < 4; ++i) gll16(aptr[i] + kk, As_dst + i * 2048);
#pragma unroll
        for (int i = 0; i < 4; ++i) gll16(bptr[i] + kk, Bs_dst + i * 2048);
        __syncthreads();
        const unsigned short* Ab = As + (wr * 64 + (lane & 15)) * 64 + (lane >> 4) * 8;
        const unsigned short* Bb = Bs + (wc * 64 + (lane & 15)) * 64 + (lane >> 4) * 8;
#pragma unroll
        for (int ksub = 0; ksub < 2; ++ksub) {
            bf16x8 a[4], b[4];
#pragma unroll
            for (int i = 0; i < 4; ++i) a[i] = *(const bf16x8*)(Ab + i * 16 * 64 + ksub * 32);
#pragma unroll
            for (int j = 0; j < 4; ++j) b[j] = *(const bf16x8*)(Bb + j * 16 * 64 + ksub * 32);
#pragma unroll
            for (int i = 0; i < 4; ++i)
#pragma unroll
                for (int j = 0; j < 4; ++j)
                    acc[i][j] = __builtin_amdgcn_mfma_f32_16x16x32_bf16(a[i], b[j], acc[i][j], 0, 0, 0);
        }
        __syncthreads();
    }

    const int rbase = rt * 128 + wr * 64 + (lane >> 4) * 4;
    const int cbase = ct * 128 + wc * 64 + (lane & 15);
#pragma unroll
    for (int i = 0; i < 4; ++i) {
#pragma unroll
        for (int r = 0; r < 4; ++r) {
            const int lr = rbase + i * 16 + r;
            if (lr < n_e) {
                const int token = perm[off + lr];
                const float w = pw[off + lr];
                float* dst = y + (size_t)token * H_DIM + cbase;
#pragma unroll
                for (int j = 0; j < 4; ++j)
                    atomicAdd(dst + j * 16, w * acc[i][j][r]);
            }
        }
    }
}

extern "C" void kernel_launch(void* const* d_in, const int* in_sizes, int n_in,
                              void* d_out, int out_size, void* d_ws, size_t ws_size,
                              hipStream_t stream) {
    const float* x  = (const float*)d_in[0];
    const float* gw = (const float*)d_in[1];
    const float* w1 = (const float*)d_in[2];
    const float* w2 = (const float*)d_in[3];
    float* y = (float*)d_out;  // [N_TOK*H_DIM] + aux at [N_TOK*H_DIM]

    // ---- workspace layout (all 16B-aligned sizes) ----
    char* base = (char*)d_ws;
    size_t o = 0;
    unsigned short* xbf  = (unsigned short*)(base + o); o += (size_t)N_TOK * H_DIM * 2;
    unsigned short* w1bf = (unsigned short*)(base + o); o += (size_t)NEXP * I_DIM * H_DIM * 2;
    unsigned short* w2bf = (unsigned short*)(base + o); o += (size_t)NEXP * H_DIM * I_DIM * 2;
    int*   topidx = (int*)(base + o);   o += (size_t)N_TOK * 2 * 4;
    float* topw   = (float*)(base + o); o += (size_t)N_TOK * 2 * 4;
    int*   perm   = (int*)(base + o);   o += (size_t)N_TOK * 2 * 4;
    float* pw     = (float*)(base + o); o += (size_t)N_TOK * 2 * 4;
    float* cnt_psum = (float*)(base + o); o += 64;
    int*   offs     = (int*)(base + o);   o += 64;
    unsigned short* hbuf = (unsigned short*)(base + o);
    size_t remain = (ws_size > o) ? (ws_size - o) : 0;

    // pick largest I-chunk that fits: h buffer = 2N * ichunk * 2 bytes
    const int opts[5] = {3072, 1536, 768, 384, 128};
    int ichunk = 128;
    for (int c = 0; c < 5; ++c) {
        if ((size_t)2 * N_TOK * opts[c] * 2 <= remain) { ichunk = opts[c]; break; }
    }

    hipMemsetAsync(d_out, 0, (size_t)out_size * 4, stream);
    hipMemsetAsync(cnt_psum, 0, 64, stream);

    // router fuses the x fp32->bf16 convert (gw staged in LDS, no spill)
    moe_router<<<1024, 256, 0, stream>>>(x, gw, xbf, topidx, topw, cnt_psum);

    moe_cvt<<<2048, 256, 0, stream>>>(w1, w1bf, NEXP * I_DIM * H_DIM);
    moe_cvt<<<2048, 256, 0, stream>>>(w2, w2bf, NEXP * H_DIM * I_DIM);

    moe_finalize<<<1, 1, 0, stream>>>(cnt_psum, offs, y + (size_t)N_TOK * H_DIM);
    moe_permute<<<8, 256, 0, stream>>>(topidx, topw, offs, perm, pw);

    for (int cb = 0; cb < I_DIM; cb += ichunk) {
        moe_gemm1<<<dim3(ichunk / 128, 128, NEXP), 256, 0, stream>>>(
            xbf, w1bf, perm, offs, hbuf, cb, ichunk);
        moe_gemm2<<<dim3(H_DIM / 128, 128, NEXP), 256, 0, stream>>>(
            hbuf, w2bf, perm, pw, offs, y, cb, ichunk);
    }
}

// Round 4
// 876.298 us; speedup vs baseline: 2.8997x; 1.9065x over previous
//
#include <hip/hip_runtime.h>
#include <hip/hip_bf16.h>

#define N_TOK 16384
#define H_DIM 768
#define I_DIM 3072
#define NEXP 8
#define RBLK 1024   // router grid; finalize depends on this

typedef short bf16x8 __attribute__((ext_vector_type(8)));
typedef float f32x4 __attribute__((ext_vector_type(4)));

__device__ __forceinline__ unsigned short f2bf(float f) {
    unsigned int u = __float_as_uint(f);
    u += 0x7fffu + ((u >> 16) & 1u);
    return (unsigned short)(u >> 16);
}

__device__ __forceinline__ float gelu_tanh(float v) {
    float u = 0.7978845608028654f * (v + 0.044715f * v * v * v);
    float t = __expf(2.0f * fminf(u, 15.0f));
    return 0.5f * v * (1.0f + (t - 1.0f) / (t + 1.0f));
}

__device__ __forceinline__ void gll16(const void* g, void* l) {
    __builtin_amdgcn_global_load_lds(
        (const __attribute__((address_space(1))) unsigned int*)g,
        (__attribute__((address_space(3))) unsigned int*)l, 16, 0, 0);
}

// ---------------- Router: logits -> softmax -> top2 -> weights (+ fused x->bf16) ----
// gw staged in LDS; x read float4, xbf written ushort4. NO global atomics:
// per-block count/psum partials -> partials[block*16 + c], reduced in moe_finalize.
__global__ __launch_bounds__(256) void moe_router(
    const float* __restrict__ x, const float* __restrict__ gw,
    unsigned short* __restrict__ xbf,
    int* __restrict__ topidx, float* __restrict__ topw,
    float* __restrict__ partials /* [RBLK*16]: counts 0..7, psum 8..15 */)
{
    __shared__ float gws[NEXP * H_DIM];  // 24 KB
    __shared__ float red[64];
    const int tid = threadIdx.x;
    for (int i = tid * 4; i < NEXP * H_DIM; i += 1024)
        *(float4*)(gws + i) = *(const float4*)(gw + i);
    __syncthreads();

    const int lane = tid & 63;
    const int wid = tid >> 6;
    const int wglobal = blockIdx.x * 4 + wid;
    const int NWAVES = RBLK * 4;

    float lcnt[8], lps[8];
#pragma unroll
    for (int e = 0; e < 8; ++e) { lcnt[e] = 0.f; lps[e] = 0.f; }

    for (int t = wglobal; t < N_TOK; t += NWAVES) {
        float acc[8] = {0.f, 0.f, 0.f, 0.f, 0.f, 0.f, 0.f, 0.f};
#pragma unroll
        for (int j = 0; j < 3; ++j) {
            const int col = j * 256 + lane * 4;
            float4 xv = *(const float4*)(x + (size_t)t * H_DIM + col);
            ushort4 o;
            o.x = f2bf(xv.x); o.y = f2bf(xv.y); o.z = f2bf(xv.z); o.w = f2bf(xv.w);
            *(ushort4*)(xbf + (size_t)t * H_DIM + col) = o;
#pragma unroll
            for (int e = 0; e < 8; ++e) {
                float4 g = *(const float4*)(gws + e * H_DIM + col);
                acc[e] += xv.x * g.x + xv.y * g.y + xv.z * g.z + xv.w * g.w;
            }
        }
#pragma unroll
        for (int off = 32; off >= 1; off >>= 1)
#pragma unroll
            for (int e = 0; e < 8; ++e) acc[e] += __shfl_xor(acc[e], off, 64);

        // top-2 on logits (same order as probs; strict > keeps lowest index on ties)
        int e0 = 0;
#pragma unroll
        for (int e = 1; e < 8; ++e) if (acc[e] > acc[e0]) e0 = e;
        int e1 = (e0 == 0) ? 1 : 0;
#pragma unroll
        for (int e = 0; e < 8; ++e) if (e != e0 && acc[e] > acc[e1]) e1 = e;

        float mx = acc[0];
#pragma unroll
        for (int e = 1; e < 8; ++e) mx = fmaxf(mx, acc[e]);
        float p[8]; float s = 0.f;
#pragma unroll
        for (int e = 0; e < 8; ++e) { p[e] = expf(acc[e] - mx); s += p[e]; }
        float inv = 1.0f / s;
#pragma unroll
        for (int e = 0; e < 8; ++e) p[e] *= inv;

        float wsum = p[e0] + p[e1];
        if (lane == 0) {
            topidx[2 * t] = e0; topidx[2 * t + 1] = e1;
            topw[2 * t] = p[e0] / wsum; topw[2 * t + 1] = p[e1] / wsum;
            lcnt[e0] += 1.f; lcnt[e1] += 1.f;
#pragma unroll
            for (int e = 0; e < 8; ++e) lps[e] += p[e];
        }
    }

    // block-level reduction of counts/psums (no atomics anywhere)
    if (lane == 0) {
#pragma unroll
        for (int e = 0; e < 8; ++e) {
            red[wid * 16 + e] = lcnt[e];
            red[wid * 16 + 8 + e] = lps[e];
        }
    }
    __syncthreads();
    if (tid < 16)
        partials[blockIdx.x * 16 + tid] =
            red[tid] + red[16 + tid] + red[32 + tid] + red[48 + tid];
}

// ---------------- reduce partials -> offsets + aux loss ----------------
__global__ __launch_bounds__(256) void moe_finalize(
    const float* __restrict__ partials, int* __restrict__ offs,
    float* __restrict__ aux_out)
{
    __shared__ float sdata[256];
    __shared__ float tot[16];
    const int tid = threadIdx.x;
    const int c = tid & 15;
    const int rg = tid >> 4;  // 0..15
    float s = 0.f;
    for (int r = rg; r < RBLK; r += 16)
        s += partials[r * 16 + c];   // coalesced: tids 0..255 cover 256 consecutive floats
    sdata[tid] = s;
    __syncthreads();
    if (tid < 16) {
        float t = 0.f;
#pragma unroll
        for (int k = 0; k < 16; ++k) t += sdata[k * 16 + tid];
        tot[tid] = t;
    }
    __syncthreads();
    if (tid == 0) {
        float aux = 0.f; int run = 0;
        for (int e = 0; e < 8; ++e) {
            float cnt = tot[e];
            aux += (cnt / (float)(N_TOK * 2)) * (tot[8 + e] / (float)N_TOK);
            offs[e] = run;
            run += (int)(cnt + 0.5f);
        }
        offs[8] = run;
        *aux_out = 0.01f * 8.0f * aux;
    }
}

// ---------------- deterministic permutation (one block per expert) ----------------
__global__ __launch_bounds__(256) void moe_permute(
    const int* __restrict__ topidx, const float* __restrict__ topw,
    const int* __restrict__ offs, int* __restrict__ perm, float* __restrict__ pw)
{
    const int e = blockIdx.x;
    const int tid = threadIdx.x;
    const int lane = tid & 63, wid = tid >> 6;
    __shared__ int wsum[4];
    __shared__ int sbase;
    if (tid == 0) sbase = offs[e];
    __syncthreads();
    for (int t0 = 0; t0 < N_TOK; t0 += 256) {
        const int t = t0 + tid;
        int slot = -1;
        if (topidx[2 * t] == e) slot = 0;
        else if (topidx[2 * t + 1] == e) slot = 1;
        unsigned long long m = __ballot(slot >= 0);
        int before = __popcll(m & ((1ull << lane) - 1ull));
        if (lane == 0) wsum[wid] = __popcll(m);
        __syncthreads();
        int wprev = 0;
        for (int w = 0; w < wid; ++w) wprev += wsum[w];
        int total = wsum[0] + wsum[1] + wsum[2] + wsum[3];
        if (slot >= 0) {
            int r = sbase + wprev + before;
            perm[r] = t;
            pw[r] = topw[2 * t + slot];
        }
        __syncthreads();
        if (tid == 0) sbase += total;
        __syncthreads();
    }
}

// ---------------- fp32 -> bf16 convert ----------------
__global__ __launch_bounds__(256) void moe_cvt(const float* __restrict__ in,
                                               unsigned short* __restrict__ out, int n)
{
    int idx = (blockIdx.x * 256 + threadIdx.x) * 4;
    const int stride = gridDim.x * 1024;
    for (; idx < n; idx += stride) {
        float4 v = *(const float4*)(in + idx);
        ushort4 o;
        o.x = f2bf(v.x); o.y = f2bf(v.y); o.z = f2bf(v.z); o.w = f2bf(v.w);
        *(ushort4*)(out + idx) = o;
    }
}

// ---------------- GEMM1: h = gelu(gather(x) @ w1[e]^T) -> bf16 ----------------
__global__ __launch_bounds__(256) void moe_gemm1(
    const unsigned short* __restrict__ xbf,
    const unsigned short* __restrict__ w1bf,
    const int* __restrict__ perm, const int* __restrict__ offs,
    unsigned short* __restrict__ hbuf, int chunk_base, int ichunk)
{
    const int e = blockIdx.z;
    const int off = offs[e];
    const int n_e = offs[e + 1] - off;
    const int rt = blockIdx.y;
    if (rt * 128 >= n_e) return;
    const int ct = blockIdx.x;

    __shared__ __align__(16) unsigned short As[128 * 64];
    __shared__ __align__(16) unsigned short Bs[128 * 64];

    const int tid = threadIdx.x;
    const int lane = tid & 63;
    const int wid = tid >> 6;
    const int wr = wid >> 1, wc = wid & 1;
    const int trow = tid >> 3;        // 0..31
    const int tcol = (tid & 7) * 8;   // 0..56

    const unsigned short* aptr[4];
    const unsigned short* bptr[4];
#pragma unroll
    for (int i = 0; i < 4; ++i) {
        int lr = rt * 128 + i * 32 + trow;
        if (lr >= n_e) lr = n_e - 1;
        const int token = perm[off + lr];
        aptr[i] = xbf + (size_t)token * H_DIM + tcol;
        const int n = chunk_base + ct * 128 + i * 32 + trow;
        bptr[i] = w1bf + ((size_t)e * I_DIM + n) * H_DIM + tcol;
    }
    unsigned short* As_dst = As + tid * 8;
    unsigned short* Bs_dst = Bs + tid * 8;

    f32x4 acc[4][4] = {};

    for (int kk = 0; kk < H_DIM; kk += 64) {
#pragma unroll
        for (int i = 0; i < 4; ++i) gll16(aptr[i] + kk, As_dst + i * 2048);
#pragma unroll
        for (int i = 0; i < 4; ++i) gll16(bptr[i] + kk, Bs_dst + i * 2048);
        __syncthreads();
        const unsigned short* Ab = As + (wr * 64 + (lane & 15)) * 64 + (lane >> 4) * 8;
        const unsigned short* Bb = Bs + (wc * 64 + (lane & 15)) * 64 + (lane >> 4) * 8;
#pragma unroll
        for (int ksub = 0; ksub < 2; ++ksub) {
            bf16x8 a[4], b[4];
#pragma unroll
            for (int i = 0; i < 4; ++i) a[i] = *(const bf16x8*)(Ab + i * 16 * 64 + ksub * 32);
#pragma unroll
            for (int j = 0; j < 4; ++j) b[j] = *(const bf16x8*)(Bb + j * 16 * 64 + ksub * 32);
#pragma unroll
            for (int i = 0; i < 4; ++i)
#pragma unroll
                for (int j = 0; j < 4; ++j)
                    acc[i][j] = __builtin_amdgcn_mfma_f32_16x16x32_bf16(a[i], b[j], acc[i][j], 0, 0, 0);
        }
        __syncthreads();
    }

    const int rbase = rt * 128 + wr * 64 + (lane >> 4) * 4;
    const int cbase = ct * 128 + wc * 64 + (lane & 15);
#pragma unroll
    for (int i = 0; i < 4; ++i) {
#pragma unroll
        for (int r = 0; r < 4; ++r) {
            const int lr = rbase + i * 16 + r;
            if (lr < n_e) {
                unsigned short* dst = hbuf + (size_t)(off + lr) * ichunk + cbase;
#pragma unroll
                for (int j = 0; j < 4; ++j)
                    dst[j * 16] = f2bf(gelu_tanh(acc[i][j][r]));
            }
        }
    }
}

// ---------------- GEMM2: y += w * (h @ w2[e]^T) (weighted scatter-add) ----------------
__global__ __launch_bounds__(256) void moe_gemm2(
    const unsigned short* __restrict__ hbuf,
    const unsigned short* __restrict__ w2bf,
    const int* __restrict__ perm, const float* __restrict__ pw,
    const int* __restrict__ offs, float* __restrict__ y,
    int chunk_base, int ichunk)
{
    const int e = blockIdx.z;
    const int off = offs[e];
    const int n_e = offs[e + 1] - off;
    const int rt = blockIdx.y;
    if (rt * 128 >= n_e) return;
    const int ct = blockIdx.x;  // 0..5

    __shared__ __align__(16) unsigned short As[128 * 64];
    __shared__ __align__(16) unsigned short Bs[128 * 64];

    const int tid = threadIdx.x;
    const int lane = tid & 63;
    const int wid = tid >> 6;
    const int wr = wid >> 1, wc = wid & 1;
    const int trow = tid >> 3, tcol = (tid & 7) * 8;

    const unsigned short* aptr[4];
    const unsigned short* bptr[4];
#pragma unroll
    for (int i = 0; i < 4; ++i) {
        int lr = rt * 128 + i * 32 + trow;
        if (lr >= n_e) lr = n_e - 1;
        aptr[i] = hbuf + (size_t)(off + lr) * ichunk + tcol;
        const int n = ct * 128 + i * 32 + trow;
        bptr[i] = w2bf + ((size_t)e * H_DIM + n) * I_DIM + chunk_base + tcol;
    }
    unsigned short* As_dst = As + tid * 8;
    unsigned short* Bs_dst = Bs + tid * 8;

    f32x4 acc[4][4] = {};

    for (int kk = 0; kk < ichunk; kk += 64) {
#pragma unroll
        for (int i = 0; i < 4; ++i) gll16(aptr[i] + kk, As_dst + i * 2048);
#pragma unroll
        for (int i = 0; i < 4; ++i) gll16(bptr[i] + kk, Bs_dst + i * 2048);
        __syncthreads();
        const unsigned short* Ab = As + (wr * 64 + (lane & 15)) * 64 + (lane >> 4) * 8;
        const unsigned short* Bb = Bs + (wc * 64 + (lane & 15)) * 64 + (lane >> 4) * 8;
#pragma unroll
        for (int ksub = 0; ksub < 2; ++ksub) {
            bf16x8 a[4], b[4];
#pragma unroll
            for (int i = 0; i < 4; ++i) a[i] = *(const bf16x8*)(Ab + i * 16 * 64 + ksub * 32);
#pragma unroll
            for (int j = 0; j < 4; ++j) b[j] = *(const bf16x8*)(Bb + j * 16 * 64 + ksub * 32);
#pragma unroll
            for (int i = 0; i < 4; ++i)
#pragma unroll
                for (int j = 0; j < 4; ++j)
                    acc[i][j] = __builtin_amdgcn_mfma_f32_16x16x32_bf16(a[i], b[j], acc[i][j], 0, 0, 0);
        }
        __syncthreads();
    }

    const int rbase = rt * 128 + wr * 64 + (lane >> 4) * 4;
    const int cbase = ct * 128 + wc * 64 + (lane & 15);
#pragma unroll
    for (int i = 0; i < 4; ++i) {
#pragma unroll
        for (int r = 0; r < 4; ++r) {
            const int lr = rbase + i * 16 + r;
            if (lr < n_e) {
                const int token = perm[off + lr];
                const float w = pw[off + lr];
                float* dst = y + (size_t)token * H_DIM + cbase;
#pragma unroll
                for (int j = 0; j < 4; ++j)
                    atomicAdd(dst + j * 16, w * acc[i][j][r]);
            }
        }
    }
}

extern "C" void kernel_launch(void* const* d_in, const int* in_sizes, int n_in,
                              void* d_out, int out_size, void* d_ws, size_t ws_size,
                              hipStream_t stream) {
    const float* x  = (const float*)d_in[0];
    const float* gw = (const float*)d_in[1];
    const float* w1 = (const float*)d_in[2];
    const float* w2 = (const float*)d_in[3];
    float* y = (float*)d_out;  // [N_TOK*H_DIM] + aux at [N_TOK*H_DIM]

    // ---- workspace layout (all 16B-aligned sizes) ----
    char* base = (char*)d_ws;
    size_t o = 0;
    unsigned short* xbf  = (unsigned short*)(base + o); o += (size_t)N_TOK * H_DIM * 2;
    unsigned short* w1bf = (unsigned short*)(base + o); o += (size_t)NEXP * I_DIM * H_DIM * 2;
    unsigned short* w2bf = (unsigned short*)(base + o); o += (size_t)NEXP * H_DIM * I_DIM * 2;
    int*   topidx = (int*)(base + o);   o += (size_t)N_TOK * 2 * 4;
    float* topw   = (float*)(base + o); o += (size_t)N_TOK * 2 * 4;
    int*   perm   = (int*)(base + o);   o += (size_t)N_TOK * 2 * 4;
    float* pw     = (float*)(base + o); o += (size_t)N_TOK * 2 * 4;
    float* partials = (float*)(base + o); o += (size_t)RBLK * 16 * 4;
    int*   offs     = (int*)(base + o);   o += 64;
    unsigned short* hbuf = (unsigned short*)(base + o);
    size_t remain = (ws_size > o) ? (ws_size - o) : 0;

    // pick largest I-chunk that fits: h buffer = 2N * ichunk * 2 bytes
    const int opts[5] = {3072, 1536, 768, 384, 128};
    int ichunk = 128;
    for (int c = 0; c < 5; ++c) {
        if ((size_t)2 * N_TOK * opts[c] * 2 <= remain) { ichunk = opts[c]; break; }
    }

    hipMemsetAsync(d_out, 0, (size_t)out_size * 4, stream);

    // router fuses the x fp32->bf16 convert; no global atomics
    moe_router<<<RBLK, 256, 0, stream>>>(x, gw, xbf, topidx, topw, partials);

    moe_cvt<<<2048, 256, 0, stream>>>(w1, w1bf, NEXP * I_DIM * H_DIM);
    moe_cvt<<<2048, 256, 0, stream>>>(w2, w2bf, NEXP * H_DIM * I_DIM);

    moe_finalize<<<1, 256, 0, stream>>>(partials, offs, y + (size_t)N_TOK * H_DIM);
    moe_permute<<<8, 256, 0, stream>>>(topidx, topw, offs, perm, pw);

    for (int cb = 0; cb < I_DIM; cb += ichunk) {
        moe_gemm1<<<dim3(ichunk / 128, 128, NEXP), 256, 0, stream>>>(
            xbf, w1bf, perm, offs, hbuf, cb, ichunk);
        moe_gemm2<<<dim3(H_DIM / 128, 128, NEXP), 256, 0, stream>>>(
            hbuf, w2bf, perm, pw, offs, y, cb, ichunk);
    }
}

// Round 5
// 776.782 us; speedup vs baseline: 3.2712x; 1.1281x over previous
//
#include <hip/hip_runtime.h>
#include <hip/hip_bf16.h>

#define N_TOK 16384
#define H_DIM 768
#define I_DIM 3072
#define NEXP 8
#define RBLK 1024   // router grid; finalize depends on this

typedef short bf16x8 __attribute__((ext_vector_type(8)));
typedef float f32x4 __attribute__((ext_vector_type(4)));

__device__ __forceinline__ unsigned short f2bf(float f) {
    unsigned int u = __float_as_uint(f);
    u += 0x7fffu + ((u >> 16) & 1u);
    return (unsigned short)(u >> 16);
}

__device__ __forceinline__ float gelu_tanh(float v) {
    float u = 0.7978845608028654f * (v + 0.044715f * v * v * v);
    float t = __expf(2.0f * fminf(u, 15.0f));
    return 0.5f * v * (1.0f + (t - 1.0f) / (t + 1.0f));
}

__device__ __forceinline__ void gll16(const void* g, void* l) {
    __builtin_amdgcn_global_load_lds(
        (const __attribute__((address_space(1))) unsigned int*)g,
        (__attribute__((address_space(3))) unsigned int*)l, 16, 0, 0);
}

// ---------------- Router: logits -> softmax -> top2 -> weights (+ fused x->bf16) ----
__global__ __launch_bounds__(256) void moe_router(
    const float* __restrict__ x, const float* __restrict__ gw,
    unsigned short* __restrict__ xbf,
    int* __restrict__ topidx, float* __restrict__ topw,
    float* __restrict__ partials /* [RBLK*16]: counts 0..7, psum 8..15 */)
{
    __shared__ float gws[NEXP * H_DIM];  // 24 KB
    __shared__ float red[64];
    const int tid = threadIdx.x;
    for (int i = tid * 4; i < NEXP * H_DIM; i += 1024)
        *(float4*)(gws + i) = *(const float4*)(gw + i);
    __syncthreads();

    const int lane = tid & 63;
    const int wid = tid >> 6;
    const int wglobal = blockIdx.x * 4 + wid;
    const int NWAVES = RBLK * 4;

    float lcnt[8], lps[8];
#pragma unroll
    for (int e = 0; e < 8; ++e) { lcnt[e] = 0.f; lps[e] = 0.f; }

    for (int t = wglobal; t < N_TOK; t += NWAVES) {
        float acc[8] = {0.f, 0.f, 0.f, 0.f, 0.f, 0.f, 0.f, 0.f};
#pragma unroll
        for (int j = 0; j < 3; ++j) {
            const int col = j * 256 + lane * 4;
            float4 xv = *(const float4*)(x + (size_t)t * H_DIM + col);
            ushort4 o;
            o.x = f2bf(xv.x); o.y = f2bf(xv.y); o.z = f2bf(xv.z); o.w = f2bf(xv.w);
            *(ushort4*)(xbf + (size_t)t * H_DIM + col) = o;
#pragma unroll
            for (int e = 0; e < 8; ++e) {
                float4 g = *(const float4*)(gws + e * H_DIM + col);
                acc[e] += xv.x * g.x + xv.y * g.y + xv.z * g.z + xv.w * g.w;
            }
        }
#pragma unroll
        for (int off = 32; off >= 1; off >>= 1)
#pragma unroll
            for (int e = 0; e < 8; ++e) acc[e] += __shfl_xor(acc[e], off, 64);

        // top-2 on logits (same order as probs; strict > keeps lowest index on ties)
        int e0 = 0;
#pragma unroll
        for (int e = 1; e < 8; ++e) if (acc[e] > acc[e0]) e0 = e;
        int e1 = (e0 == 0) ? 1 : 0;
#pragma unroll
        for (int e = 0; e < 8; ++e) if (e != e0 && acc[e] > acc[e1]) e1 = e;

        float mx = acc[0];
#pragma unroll
        for (int e = 1; e < 8; ++e) mx = fmaxf(mx, acc[e]);
        float p[8]; float s = 0.f;
#pragma unroll
        for (int e = 0; e < 8; ++e) { p[e] = expf(acc[e] - mx); s += p[e]; }
        float inv = 1.0f / s;
#pragma unroll
        for (int e = 0; e < 8; ++e) p[e] *= inv;

        float wsum = p[e0] + p[e1];
        if (lane == 0) {
            topidx[2 * t] = e0; topidx[2 * t + 1] = e1;
            topw[2 * t] = p[e0] / wsum; topw[2 * t + 1] = p[e1] / wsum;
            lcnt[e0] += 1.f; lcnt[e1] += 1.f;
#pragma unroll
            for (int e = 0; e < 8; ++e) lps[e] += p[e];
        }
    }

    // block-level reduction of counts/psums (no atomics anywhere)
    if (lane == 0) {
#pragma unroll
        for (int e = 0; e < 8; ++e) {
            red[wid * 16 + e] = lcnt[e];
            red[wid * 16 + 8 + e] = lps[e];
        }
    }
    __syncthreads();
    if (tid < 16)
        partials[blockIdx.x * 16 + tid] =
            red[tid] + red[16 + tid] + red[32 + tid] + red[48 + tid];
}

// ---------------- reduce partials -> offsets + aux loss ----------------
__global__ __launch_bounds__(256) void moe_finalize(
    const float* __restrict__ partials, int* __restrict__ offs,
    float* __restrict__ aux_out)
{
    __shared__ float sdata[256];
    __shared__ float tot[16];
    const int tid = threadIdx.x;
    const int c = tid & 15;
    const int rg = tid >> 4;  // 0..15
    float s = 0.f;
    for (int r = rg; r < RBLK; r += 16)
        s += partials[r * 16 + c];
    sdata[tid] = s;
    __syncthreads();
    if (tid < 16) {
        float t = 0.f;
#pragma unroll
        for (int k = 0; k < 16; ++k) t += sdata[k * 16 + tid];
        tot[tid] = t;
    }
    __syncthreads();
    if (tid == 0) {
        float aux = 0.f; int run = 0;
        for (int e = 0; e < 8; ++e) {
            float cnt = tot[e];
            aux += (cnt / (float)(N_TOK * 2)) * (tot[8 + e] / (float)N_TOK);
            offs[e] = run;
            run += (int)(cnt + 0.5f);
        }
        offs[8] = run;
        *aux_out = 0.01f * 8.0f * aux;
    }
}

// ---------------- deterministic permutation (one block per expert) ----------------
__global__ __launch_bounds__(256) void moe_permute(
    const int* __restrict__ topidx, const float* __restrict__ topw,
    const int* __restrict__ offs, int* __restrict__ perm, float* __restrict__ pw)
{
    const int e = blockIdx.x;
    const int tid = threadIdx.x;
    const int lane = tid & 63, wid = tid >> 6;
    __shared__ int wsum[4];
    __shared__ int sbase;
    if (tid == 0) sbase = offs[e];
    __syncthreads();
    for (int t0 = 0; t0 < N_TOK; t0 += 256) {
        const int t = t0 + tid;
        int slot = -1;
        if (topidx[2 * t] == e) slot = 0;
        else if (topidx[2 * t + 1] == e) slot = 1;
        unsigned long long m = __ballot(slot >= 0);
        int before = __popcll(m & ((1ull << lane) - 1ull));
        if (lane == 0) wsum[wid] = __popcll(m);
        __syncthreads();
        int wprev = 0;
        for (int w = 0; w < wid; ++w) wprev += wsum[w];
        int total = wsum[0] + wsum[1] + wsum[2] + wsum[3];
        if (slot >= 0) {
            int r = sbase + wprev + before;
            perm[r] = t;
            pw[r] = topw[2 * t + slot];
        }
        __syncthreads();
        if (tid == 0) sbase += total;
        __syncthreads();
    }
}

// ---------------- fp32 -> bf16 convert ----------------
__global__ __launch_bounds__(256) void moe_cvt(const float* __restrict__ in,
                                               unsigned short* __restrict__ out, int n)
{
    int idx = (blockIdx.x * 256 + threadIdx.x) * 4;
    const int stride = gridDim.x * 1024;
    for (; idx < n; idx += stride) {
        float4 v = *(const float4*)(in + idx);
        ushort4 o;
        o.x = f2bf(v.x); o.y = f2bf(v.y); o.z = f2bf(v.z); o.w = f2bf(v.w);
        *(ushort4*)(out + idx) = o;
    }
}

// T2 XOR-swizzle: LDS stays linear (global_load_lds writes base+lane*16),
// but the CONTENT is permuted by pre-swizzling the global source column:
// slot (row, c16) holds orig[row][c16 ^ (row&7)]. Reads XOR the same way.
// tcol_sw is a per-thread constant: ((tid&7) ^ (trow&7)) * 8 shorts.

// ---------------- GEMM1: h = gelu(gather(x) @ w1[e]^T) -> bf16 ----------------
__global__ __launch_bounds__(256) void moe_gemm1(
    const unsigned short* __restrict__ xbf,
    const unsigned short* __restrict__ w1bf,
    const int* __restrict__ perm, const int* __restrict__ offs,
    unsigned short* __restrict__ hbuf, int chunk_base, int ichunk)
{
    const int e = blockIdx.z;
    const int off = offs[e];
    const int n_e = offs[e + 1] - off;
    const int rt = blockIdx.y;
    if (rt * 128 >= n_e) return;
    const int ct = blockIdx.x;

    __shared__ __align__(16) unsigned short As[128 * 64];
    __shared__ __align__(16) unsigned short Bs[128 * 64];

    const int tid = threadIdx.x;
    const int lane = tid & 63;
    const int wid = tid >> 6;
    const int wr = wid >> 1, wc = wid & 1;
    const int trow = tid >> 3;        // 0..31
    const int tcol = (((tid & 7) ^ (trow & 7))) * 8;   // swizzled source column

    const unsigned short* aptr[4];
    const unsigned short* bptr[4];
#pragma unroll
    for (int i = 0; i < 4; ++i) {
        int lr = rt * 128 + i * 32 + trow;
        if (lr >= n_e) lr = n_e - 1;
        const int token = perm[off + lr];
        aptr[i] = xbf + (size_t)token * H_DIM + tcol;
        const int n = chunk_base + ct * 128 + i * 32 + trow;
        bptr[i] = w1bf + ((size_t)e * I_DIM + n) * H_DIM + tcol;
    }
    unsigned short* As_dst = As + tid * 8;
    unsigned short* Bs_dst = Bs + tid * 8;

    // swizzled read columns (shorts): c16 = (lane>>4) + ksub*4, XOR row&7 (= lane&7)
    const int rA = (wr * 64 + (lane & 15)) * 64;
    const int rB = (wc * 64 + (lane & 15)) * 64;
    const int cs0 = (((lane >> 4)    ) ^ (lane & 7)) * 8;
    const int cs1 = (((lane >> 4) + 4) ^ (lane & 7)) * 8;

    f32x4 acc[4][4] = {};

    for (int kk = 0; kk < H_DIM; kk += 64) {
#pragma unroll
        for (int i = 0; i < 4; ++i) gll16(aptr[i] + kk, As_dst + i * 2048);
#pragma unroll
        for (int i = 0; i < 4; ++i) gll16(bptr[i] + kk, Bs_dst + i * 2048);
        __syncthreads();
#pragma unroll
        for (int ksub = 0; ksub < 2; ++ksub) {
            const int cs = ksub ? cs1 : cs0;
            bf16x8 a[4], b[4];
#pragma unroll
            for (int i = 0; i < 4; ++i) a[i] = *(const bf16x8*)(As + rA + i * 1024 + cs);
#pragma unroll
            for (int j = 0; j < 4; ++j) b[j] = *(const bf16x8*)(Bs + rB + j * 1024 + cs);
#pragma unroll
            for (int i = 0; i < 4; ++i)
#pragma unroll
                for (int j = 0; j < 4; ++j)
                    acc[i][j] = __builtin_amdgcn_mfma_f32_16x16x32_bf16(a[i], b[j], acc[i][j], 0, 0, 0);
        }
        __syncthreads();
    }

    const int rbase = rt * 128 + wr * 64 + (lane >> 4) * 4;
    const int cbase = ct * 128 + wc * 64 + (lane & 15);
#pragma unroll
    for (int i = 0; i < 4; ++i) {
#pragma unroll
        for (int r = 0; r < 4; ++r) {
            const int lr = rbase + i * 16 + r;
            if (lr < n_e) {
                unsigned short* dst = hbuf + (size_t)(off + lr) * ichunk + cbase;
#pragma unroll
                for (int j = 0; j < 4; ++j)
                    dst[j * 16] = f2bf(gelu_tanh(acc[i][j][r]));
            }
        }
    }
}

// ---------------- GEMM2: y += w * (h @ w2[e]^T) (weighted scatter-add) ----------------
__global__ __launch_bounds__(256) void moe_gemm2(
    const unsigned short* __restrict__ hbuf,
    const unsigned short* __restrict__ w2bf,
    const int* __restrict__ perm, const float* __restrict__ pw,
    const int* __restrict__ offs, float* __restrict__ y,
    int chunk_base, int ichunk)
{
    const int e = blockIdx.z;
    const int off = offs[e];
    const int n_e = offs[e + 1] - off;
    const int rt = blockIdx.y;
    if (rt * 128 >= n_e) return;
    const int ct = blockIdx.x;  // 0..5

    __shared__ __align__(16) unsigned short As[128 * 64];
    __shared__ __align__(16) unsigned short Bs[128 * 64];

    const int tid = threadIdx.x;
    const int lane = tid & 63;
    const int wid = tid >> 6;
    const int wr = wid >> 1, wc = wid & 1;
    const int trow = tid >> 3;
    const int tcol = (((tid & 7) ^ (trow & 7))) * 8;   // swizzled source column

    const unsigned short* aptr[4];
    const unsigned short* bptr[4];
#pragma unroll
    for (int i = 0; i < 4; ++i) {
        int lr = rt * 128 + i * 32 + trow;
        if (lr >= n_e) lr = n_e - 1;
        aptr[i] = hbuf + (size_t)(off + lr) * ichunk + tcol;
        const int n = ct * 128 + i * 32 + trow;
        bptr[i] = w2bf + ((size_t)e * H_DIM + n) * I_DIM + chunk_base + tcol;
    }
    unsigned short* As_dst = As + tid * 8;
    unsigned short* Bs_dst = Bs + tid * 8;

    const int rA = (wr * 64 + (lane & 15)) * 64;
    const int rB = (wc * 64 + (lane & 15)) * 64;
    const int cs0 = (((lane >> 4)    ) ^ (lane & 7)) * 8;
    const int cs1 = (((lane >> 4) + 4) ^ (lane & 7)) * 8;

    f32x4 acc[4][4] = {};

    for (int kk = 0; kk < ichunk; kk += 64) {
#pragma unroll
        for (int i = 0; i < 4; ++i) gll16(aptr[i] + kk, As_dst + i * 2048);
#pragma unroll
        for (int i = 0; i < 4; ++i) gll16(bptr[i] + kk, Bs_dst + i * 2048);
        __syncthreads();
#pragma unroll
        for (int ksub = 0; ksub < 2; ++ksub) {
            const int cs = ksub ? cs1 : cs0;
            bf16x8 a[4], b[4];
#pragma unroll
            for (int i = 0; i < 4; ++i) a[i] = *(const bf16x8*)(As + rA + i * 1024 + cs);
#pragma unroll
            for (int j = 0; j < 4; ++j) b[j] = *(const bf16x8*)(Bs + rB + j * 1024 + cs);
#pragma unroll
            for (int i = 0; i < 4; ++i)
#pragma unroll
                for (int j = 0; j < 4; ++j)
                    acc[i][j] = __builtin_amdgcn_mfma_f32_16x16x32_bf16(a[i], b[j], acc[i][j], 0, 0, 0);
        }
        __syncthreads();
    }

    const int rbase = rt * 128 + wr * 64 + (lane >> 4) * 4;
    const int cbase = ct * 128 + wc * 64 + (lane & 15);
#pragma unroll
    for (int i = 0; i < 4; ++i) {
#pragma unroll
        for (int r = 0; r < 4; ++r) {
            const int lr = rbase + i * 16 + r;
            if (lr < n_e) {
                const int token = perm[off + lr];
                const float w = pw[off + lr];
                float* dst = y + (size_t)token * H_DIM + cbase;
#pragma unroll
                for (int j = 0; j < 4; ++j)
                    atomicAdd(dst + j * 16, w * acc[i][j][r]);
            }
        }
    }
}

extern "C" void kernel_launch(void* const* d_in, const int* in_sizes, int n_in,
                              void* d_out, int out_size, void* d_ws, size_t ws_size,
                              hipStream_t stream) {
    const float* x  = (const float*)d_in[0];
    const float* gw = (const float*)d_in[1];
    const float* w1 = (const float*)d_in[2];
    const float* w2 = (const float*)d_in[3];
    float* y = (float*)d_out;  // [N_TOK*H_DIM] + aux at [N_TOK*H_DIM]

    // ---- workspace layout (all 16B-aligned sizes) ----
    char* base = (char*)d_ws;
    size_t o = 0;
    unsigned short* xbf  = (unsigned short*)(base + o); o += (size_t)N_TOK * H_DIM * 2;
    unsigned short* w1bf = (unsigned short*)(base + o); o += (size_t)NEXP * I_DIM * H_DIM * 2;
    unsigned short* w2bf = (unsigned short*)(base + o); o += (size_t)NEXP * H_DIM * I_DIM * 2;
    int*   topidx = (int*)(base + o);   o += (size_t)N_TOK * 2 * 4;
    float* topw   = (float*)(base + o); o += (size_t)N_TOK * 2 * 4;
    int*   perm   = (int*)(base + o);   o += (size_t)N_TOK * 2 * 4;
    float* pw     = (float*)(base + o); o += (size_t)N_TOK * 2 * 4;
    float* partials = (float*)(base + o); o += (size_t)RBLK * 16 * 4;
    int*   offs     = (int*)(base + o);   o += 64;
    unsigned short* hbuf = (unsigned short*)(base + o);
    size_t remain = (ws_size > o) ? (ws_size - o) : 0;

    // pick largest I-chunk that fits: h buffer = 2N * ichunk * 2 bytes
    const int opts[5] = {3072, 1536, 768, 384, 128};
    int ichunk = 128;
    for (int c = 0; c < 5; ++c) {
        if ((size_t)2 * N_TOK * opts[c] * 2 <= remain) { ichunk = opts[c]; break; }
    }

    hipMemsetAsync(d_out, 0, (size_t)out_size * 4, stream);

    // router fuses the x fp32->bf16 convert; no global atomics
    moe_router<<<RBLK, 256, 0, stream>>>(x, gw, xbf, topidx, topw, partials);

    moe_cvt<<<2048, 256, 0, stream>>>(w1, w1bf, NEXP * I_DIM * H_DIM);
    moe_cvt<<<2048, 256, 0, stream>>>(w2, w2bf, NEXP * H_DIM * I_DIM);

    moe_finalize<<<1, 256, 0, stream>>>(partials, offs, y + (size_t)N_TOK * H_DIM);
    moe_permute<<<8, 256, 0, stream>>>(topidx, topw, offs, perm, pw);

    for (int cb = 0; cb < I_DIM; cb += ichunk) {
        moe_gemm1<<<dim3(ichunk / 128, 128, NEXP), 256, 0, stream>>>(
            xbf, w1bf, perm, offs, hbuf, cb, ichunk);
        moe_gemm2<<<dim3(H_DIM / 128, 128, NEXP), 256, 0, stream>>>(
            hbuf, w2bf, perm, pw, offs, y, cb, ichunk);
    }
}